// Round 3
// baseline (19593.488 us; speedup 1.0000x reference)
//
#include <hip/hip_runtime.h>
#include <hip/hip_bf16.h>

#define VOCAB 50000
#define EMB   300
#define HID   1024
#define TT    512
#define BB    64
#define M_ROWS (BB * TT)   // 32768 rows, r = t*64 + b

typedef __attribute__((ext_vector_type(8))) short short8;
typedef __attribute__((ext_vector_type(4))) float floatx4;

__device__ inline float b2f(unsigned short u) {
    union { unsigned int i; float f; } v; v.i = ((unsigned int)u) << 16; return v.f;
}
__device__ inline unsigned short f2b(float f) {
    __hip_bfloat16 h = __float2bfloat16(f);
    return *reinterpret_cast<unsigned short*>(&h);
}

// ---------------------------------------------------------------------------
// detect: decide whether float inputs are bf16 (mode=0) or fp32 (mode=1) by
// inspecting W_hh0 ~ U(-1/32,1/32). bf16 buffer: every even-index short
// decodes to |v|<=1/32. fp32 buffer (little-endian): even-index shorts are
// the LOW mantissa halves of floats -> random 16-bit patterns, ~half decode
// with |v|>0.5 (incl. NaN/Inf). Also zeroes both scan-barrier flag sets.
// ctl layout (ints): [0]=mode, [64..127]=flagsA, [128..191]=flagsB
// Round-1/2 evidence says inputs are fp32 (mode=1); detection kept as
// insurance at ~2us cost.
// ---------------------------------------------------------------------------
__global__ __launch_bounds__(64)
void detect_kernel(const void* __restrict__ W, int* __restrict__ ctl)
{
    const int tid = threadIdx.x;
    const unsigned short* p = (const unsigned short*)W;
    int bad = 0;
    for (int i = tid; i < 1024; i += 64) {
        float v = b2f(p[2 * i]);
        if (!(v > -0.5f && v < 0.5f)) bad++;   // NaN fails both -> counted
    }
    for (int off = 32; off; off >>= 1) bad += __shfl_down(bad, off);
    if (tid == 0) ctl[0] = (bad > 16) ? 1 : 0;
    ctl[64 + tid]  = 0;   // flagsA
    ctl[128 + tid] = 0;   // flagsB
}

// ---------------------------------------------------------------------------
// proj: C[r][n] = bf16( sum_k A[r][k] * W[n][k] + bias[n] )
// GATHER=1: A row r = emb[x[b*T+t]] with b=r&63, t=r>>6, K=EMB=300.
// GATHER=0: A = internal bf16 buffer (h1), K=HID.
// W/bias/emb dtype selected at runtime via ctl[0]; W rounded to bf16 in LDS.
// Tile: 64 rows x 16 cols per WG (4 waves, one 16x16x32 MFMA tile per wave).
// ---------------------------------------------------------------------------
template<int GATHER>
__global__ __launch_bounds__(256)
void proj_kernel(const unsigned short* __restrict__ Abf,
                 const int*            __restrict__ xidx,
                 const void*           __restrict__ emb,
                 const void*           __restrict__ W,
                 const void*           __restrict__ bias,
                 unsigned short*       __restrict__ C,    // bf16 [32768][1024]
                 int K,
                 const int* __restrict__ ctl)
{
    const int mode = ctl[0];
    __shared__ unsigned short Wl[16 * 1032];
    const int tid = threadIdx.x;
    const int nb = blockIdx.x, mb = blockIdx.y;
    const int n0 = nb * 16;
    const int KP2 = (K + 15) & ~7;

    if (mode) {                       // fp32 weights -> round to bf16 in LDS
        const float* Wf = (const float*)W;
        const int e4 = K >> 2, tot = 16 * e4;      // K%4==0 for 300 and 1024
        for (int i = tid; i < tot; i += 256) {
            int nl = i / e4, c = i - nl * e4;
            float4 f = *(const float4*)(Wf + (size_t)(n0 + nl) * K + c * 4);
            unsigned short* d = &Wl[nl * KP2 + c * 4];
            d[0] = f2b(f.x); d[1] = f2b(f.y); d[2] = f2b(f.z); d[3] = f2b(f.w);
        }
    } else {
        const unsigned short* Wb = (const unsigned short*)W;
        if ((K & 7) == 0) {
            const int e8 = K >> 3, tot = 16 * e8;
            for (int i = tid; i < tot; i += 256) {
                int nl = i / e8, c = i - nl * e8;
                *(short8*)&Wl[nl * KP2 + c * 8] =
                    *(const short8*)(Wb + (size_t)(n0 + nl) * K + c * 8);
            }
        } else {
            const int tot = 16 * K;
            for (int i = tid; i < tot; i += 256) {
                int nl = i / K, c = i - nl * K;
                Wl[nl * KP2 + c] = Wb[(size_t)(n0 + nl) * K + c];
            }
        }
    }
    __syncthreads();

    const int wave = tid >> 6, lane = tid & 63;
    const int quad = lane >> 4, ln = lane & 15;
    const int r = mb * 64 + wave * 16 + ln;

    const unsigned short* Ab = nullptr;
    const float*          Af = nullptr;
    if (GATHER) {
        int t = r >> 6, b = r & 63;
        size_t off = (size_t)xidx[b * TT + t] * K;
        if (mode) Af = (const float*)emb + off;   // 1200B row stride: 16B-aligned
        else      Ab = (const unsigned short*)emb + off;
    } else {
        Ab = Abf + (size_t)r * K;
    }

    floatx4 acc = {0.f, 0.f, 0.f, 0.f};
    const int full = K >> 5, rem = K & 31;

    for (int kk = 0; kk < full; ++kk) {
        int k = kk * 32 + quad * 8;
        short8 a;
        if (GATHER && mode) {
            float4 f0 = *(const float4*)(Af + k);
            float4 f1 = *(const float4*)(Af + k + 4);
            a[0]=f2b(f0.x); a[1]=f2b(f0.y); a[2]=f2b(f0.z); a[3]=f2b(f0.w);
            a[4]=f2b(f1.x); a[5]=f2b(f1.y); a[6]=f2b(f1.z); a[7]=f2b(f1.w);
        } else if (GATHER) {
            const uint2* ap = (const uint2*)(Ab + k);   // emb rows 8B-aligned
            ((uint2*)&a)[0] = ap[0];
            ((uint2*)&a)[1] = ap[1];
        } else {
            a = *(const short8*)(Ab + k);
        }
        short8 b = *(const short8*)&Wl[ln * KP2 + k];
        acc = __builtin_amdgcn_mfma_f32_16x16x32_bf16(a, b, acc, 0, 0, 0);
    }
    if (rem) {   // K=300 tail
        short8 a, b;
        for (int j = 0; j < 8; ++j) {
            int k = full * 32 + quad * 8 + j;
            bool in = (k < K);
            unsigned short raw = 0;
            if (in) raw = (GATHER && mode) ? f2b(Af[k]) : Ab[k];
            a[j] = (short)raw;
            b[j] = in ? (short)Wl[ln * KP2 + k] : (short)0;
        }
        acc = __builtin_amdgcn_mfma_f32_16x16x32_bf16(a, b, acc, 0, 0, 0);
    }

    // C/D layout: col = lane&15, row = (lane>>4)*4 + reg  [m89/m91]
    const int col = n0 + ln;
    const float bvf = mode ? ((const float*)bias)[col]
                           : b2f(((const unsigned short*)bias)[col]);
    for (int rg = 0; rg < 4; ++rg) {
        int rr = mb * 64 + wave * 16 + quad * 4 + rg;
        C[(size_t)rr * HID + col] = f2b(acc[rg] + bvf);
    }
}

// ---------------------------------------------------------------------------
// scan: h[t] = tanh(pre[t] + h[t-1] @ Whh^T + bhh), t = 0..511
// 32 persistent WGs x 512 threads. WG owns 32 output cols; its Whh slice
// (32x1024 bf16) lives in LDS. h exchanged in global bf16 ([T][B][HID]).
// Cross-WG barrier: release fence + per-WG flag + poll + acquire fence
// (fence pair handles cross-XCD L2 non-coherence). flags pre-zeroed by detect.
// ---------------------------------------------------------------------------
__global__ __launch_bounds__(512)
void scan_kernel(const unsigned short* __restrict__ pre,  // [T][B][HID] bf16
                 unsigned short*       __restrict__ h,    // [T][B][HID] bf16
                 const void*           __restrict__ Whh,
                 const void*           __restrict__ bhh,
                 int* __restrict__ ctl, int flagOff)
{
    const int mode = ctl[0];
    int* flags = ctl + flagOff;
    __shared__ unsigned short Wl[32 * 1032];
    const int tid = threadIdx.x;
    const int n0 = blockIdx.x * 32;

    if (mode) {
        const float* Wf = (const float*)Whh;
        for (int i = tid; i < 32 * 256; i += 512) {
            int nl = i >> 8, c = i & 255;
            float4 f = *(const float4*)(Wf + ((size_t)(n0 + nl) << 10) + c * 4);
            unsigned short* d = &Wl[nl * 1032 + c * 4];
            d[0] = f2b(f.x); d[1] = f2b(f.y); d[2] = f2b(f.z); d[3] = f2b(f.w);
        }
    } else {
        const unsigned short* Wb = (const unsigned short*)Whh;
        for (int i = tid; i < 32 * 128; i += 512) {
            int nl = i >> 7, c = i & 127;
            *(short8*)&Wl[nl * 1032 + c * 8] =
                *(const short8*)(Wb + ((size_t)(n0 + nl) << 10) + c * 8);
        }
    }
    __syncthreads();

    const int wave = tid >> 6, lane = tid & 63;
    const int quad = lane >> 4, ln = lane & 15;
    const int mt = wave & 3;          // batch group of 16
    const int nt = wave >> 2;         // N-subtile (0/1)
    const int brow = mt * 16 + ln;    // batch row for A fragments
    const int nloc = nt * 16 + ln;    // local W row / output col
    const int ncol = n0 + nloc;
    const float bvf = mode ? ((const float*)bhh)[ncol]
                           : b2f(((const unsigned short*)bhh)[ncol]);
    const int b0 = mt * 16 + quad * 4;
    const unsigned short* wl = &Wl[nloc * 1032];

    for (int t = 0; t < TT; ++t) {
        floatx4 acc = {0.f, 0.f, 0.f, 0.f};
        if (t > 0) {
            const unsigned short* hp = h + (size_t)(t - 1) * (BB * HID)
                                         + (size_t)brow * HID;
            #pragma unroll
            for (int kk = 0; kk < 32; ++kk) {
                int k = kk * 32 + quad * 8;
                short8 a = *(const short8*)(hp + k);
                short8 b = *(const short8*)(wl + k);
                acc = __builtin_amdgcn_mfma_f32_16x16x32_bf16(a, b, acc, 0, 0, 0);
            }
        }
        const unsigned short* pt = pre + (size_t)t * (BB * HID);
        unsigned short* ht = h + (size_t)t * (BB * HID);
        #pragma unroll
        for (int rg = 0; rg < 4; ++rg) {
            int bi = b0 + rg;
            float v = acc[rg] + b2f(pt[(size_t)bi * HID + ncol]) + bvf;
            ht[(size_t)bi * HID + ncol] = f2b(tanhf(v));
        }
        if (t < TT - 1) {
            __threadfence();                     // release: h[t] -> coherent pt
            __syncthreads();
            if (tid == 0)
                __hip_atomic_store(&flags[blockIdx.x], t + 1,
                                   __ATOMIC_RELAXED, __HIP_MEMORY_SCOPE_AGENT);
            if (tid < 64) {
                int idx = tid & 31;
                while (__hip_atomic_load(&flags[idx], __ATOMIC_RELAXED,
                                         __HIP_MEMORY_SCOPE_AGENT) < t + 1) {}
            }
            __threadfence();                     // acquire before reading h[t]
            __syncthreads();
        }
    }
}

// ---------------------------------------------------------------------------
// fc: out[b] = sigmoid(dot(h2[T-1][b], Wfc) + bfc)
// OUTPUT IS FP32 (reference returns float32; round-2 evidence: bf16 writes
// left the upper half of the fp32-read buffer zeroed -> stub-equal absmax).
// ---------------------------------------------------------------------------
__global__ __launch_bounds__(1024)
void fc_kernel(const unsigned short* __restrict__ h,
               const void* __restrict__ Wfc,
               const void* __restrict__ bfc,
               float* __restrict__ out,
               const int* __restrict__ ctl)
{
    const int mode = ctl[0];
    const int tid = threadIdx.x;
    const int b = tid >> 4, sub = tid & 15;
    const unsigned short* hr = h + (size_t)(TT - 1) * (BB * HID) + (size_t)b * HID;
    float s = 0.f;
    for (int k = sub; k < HID; k += 16) {
        float w = mode ? ((const float*)Wfc)[k]
                       : b2f(((const unsigned short*)Wfc)[k]);
        s += b2f(hr[k]) * w;
    }
    for (int off = 8; off; off >>= 1)
        s += __shfl_down(s, off, 16);
    if (sub == 0) {
        float bv = mode ? ((const float*)bfc)[0]
                        : b2f(((const unsigned short*)bfc)[0]);
        float z = s + bv;
        out[b] = 1.f / (1.f + expf(-z));
    }
}

// ---------------------------------------------------------------------------
extern "C" void kernel_launch(void* const* d_in, const int* in_sizes, int n_in,
                              void* d_out, int out_size, void* d_ws, size_t ws_size,
                              hipStream_t stream)
{
    const int*  x    = (const int*)d_in[0];
    const void* emb  = d_in[1];
    const void* Wih0 = d_in[2];
    const void* Whh0 = d_in[3];
    const void* bih0 = d_in[4];
    const void* bhh0 = d_in[5];
    const void* Wih1 = d_in[6];
    const void* Whh1 = d_in[7];
    const void* bih1 = d_in[8];
    const void* bhh1 = d_in[9];
    const void* Wfc  = d_in[10];
    const void* bfc  = d_in[11];
    float* out = (float*)d_out;

    char* ws = (char*)d_ws;
    int*            ctl  = (int*)ws;                          // 4 KiB region
    unsigned short* pre  = (unsigned short*)(ws + 4096);      // 64 MiB bf16
    unsigned short* hbuf = (unsigned short*)(ws + 4096 + (size_t)67108864);

    dim3 pgrid(HID / 16, M_ROWS / 64);

    // dtype detect + flag zeroing
    detect_kernel<<<dim3(1), dim3(64), 0, stream>>>(Whh0, ctl);
    // layer 0 input projection (embedding gather)
    proj_kernel<1><<<pgrid, dim3(256), 0, stream>>>(
        nullptr, x, emb, Wih0, bih0, pre, EMB, ctl);
    // layer 0 recurrence
    scan_kernel<<<dim3(32), dim3(512), 0, stream>>>(pre, hbuf, Whh0, bhh0, ctl, 64);
    // layer 1 input projection (reads h1, overwrites pre)
    proj_kernel<0><<<pgrid, dim3(256), 0, stream>>>(
        hbuf, nullptr, nullptr, Wih1, bih1, pre, HID, ctl);
    // layer 1 recurrence (in place over hbuf)
    scan_kernel<<<dim3(32), dim3(512), 0, stream>>>(pre, hbuf, Whh1, bhh1, ctl, 128);
    // final FC + sigmoid
    fc_kernel<<<dim3(1), dim3(1024), 0, stream>>>(hbuf, Wfc, bfc, out, ctl);
}

// Round 4
// 8577.816 us; speedup vs baseline: 2.2842x; 2.2842x over previous
//
#include <hip/hip_runtime.h>
#include <hip/hip_bf16.h>

#define VOCAB 50000
#define EMB   300
#define HID   1024
#define TT    512
#define BB    64
#define M_ROWS (BB * TT)   // 32768 rows, r = t*64 + b

typedef __attribute__((ext_vector_type(8))) short short8;
typedef __attribute__((ext_vector_type(4))) float floatx4;

__device__ inline float b2f(unsigned short u) {
    union { unsigned int i; float f; } v; v.i = ((unsigned int)u) << 16; return v.f;
}
__device__ inline unsigned short f2b(float f) {
    __hip_bfloat16 h = __float2bfloat16(f);
    return *reinterpret_cast<unsigned short*>(&h);
}

// Wait until first (32-N) of the outstanding loads have landed, and bind the
// waited-on fragments as "+v" so the compiler cannot consume them earlier.
#define WAIT_VM16(N, A) asm volatile("s_waitcnt vmcnt(" #N ")"              \
    : "+v"((A)[0]), "+v"((A)[1]), "+v"((A)[2]), "+v"((A)[3]),               \
      "+v"((A)[4]), "+v"((A)[5]), "+v"((A)[6]), "+v"((A)[7]),               \
      "+v"((A)[8]), "+v"((A)[9]), "+v"((A)[10]), "+v"((A)[11]),             \
      "+v"((A)[12]), "+v"((A)[13]), "+v"((A)[14]), "+v"((A)[15])            \
    :: "memory")

// ---------------------------------------------------------------------------
// detect: decide whether float inputs are bf16 (mode=0) or fp32 (mode=1)
// (evidence so far: fp32). Also zeroes both scan-barrier flag regions.
// ctl ints: [0]=mode, flagsA = ctl+64 (64 flags, stride 4), flagsB = ctl+320.
// ---------------------------------------------------------------------------
__global__ __launch_bounds__(64)
void detect_kernel(const void* __restrict__ W, int* __restrict__ ctl)
{
    const int tid = threadIdx.x;
    const unsigned short* p = (const unsigned short*)W;
    int bad = 0;
    for (int i = tid; i < 1024; i += 64) {
        float v = b2f(p[2 * i]);
        if (!(v > -0.5f && v < 0.5f)) bad++;   // NaN fails both -> counted
    }
    for (int off = 32; off; off >>= 1) bad += __shfl_down(bad, off);
    if (tid == 0) ctl[0] = (bad > 16) ? 1 : 0;
    for (int i = 64 + tid; i < 576; i += 64) ctl[i] = 0;   // flagsA + flagsB
}

// ---------------------------------------------------------------------------
// proj: C[r][n] = bf16( sum_k A[r][k] * W[n][k] + bias[n] )
// GATHER=1: A row r = emb[x[b*T+t]], K=EMB=300.  GATHER=0: A=h1 bf16, K=HID.
// ---------------------------------------------------------------------------
template<int GATHER>
__global__ __launch_bounds__(256)
void proj_kernel(const unsigned short* __restrict__ Abf,
                 const int*            __restrict__ xidx,
                 const void*           __restrict__ emb,
                 const void*           __restrict__ W,
                 const void*           __restrict__ bias,
                 unsigned short*       __restrict__ C,    // bf16 [32768][1024]
                 int K,
                 const int* __restrict__ ctl)
{
    const int mode = ctl[0];
    __shared__ unsigned short Wl[16 * 1032];
    const int tid = threadIdx.x;
    const int nb = blockIdx.x, mb = blockIdx.y;
    const int n0 = nb * 16;
    const int KP2 = (K + 15) & ~7;

    if (mode) {                       // fp32 weights -> round to bf16 in LDS
        const float* Wf = (const float*)W;
        const int e4 = K >> 2, tot = 16 * e4;
        for (int i = tid; i < tot; i += 256) {
            int nl = i / e4, c = i - nl * e4;
            float4 f = *(const float4*)(Wf + (size_t)(n0 + nl) * K + c * 4);
            unsigned short* d = &Wl[nl * KP2 + c * 4];
            d[0] = f2b(f.x); d[1] = f2b(f.y); d[2] = f2b(f.z); d[3] = f2b(f.w);
        }
    } else {
        const unsigned short* Wb = (const unsigned short*)W;
        if ((K & 7) == 0) {
            const int e8 = K >> 3, tot = 16 * e8;
            for (int i = tid; i < tot; i += 256) {
                int nl = i / e8, c = i - nl * e8;
                *(short8*)&Wl[nl * KP2 + c * 8] =
                    *(const short8*)(Wb + (size_t)(n0 + nl) * K + c * 8);
            }
        } else {
            const int tot = 16 * K;
            for (int i = tid; i < tot; i += 256) {
                int nl = i / K, c = i - nl * K;
                Wl[nl * KP2 + c] = Wb[(size_t)(n0 + nl) * K + c];
            }
        }
    }
    __syncthreads();

    const int wave = tid >> 6, lane = tid & 63;
    const int quad = lane >> 4, ln = lane & 15;
    const int r = mb * 64 + wave * 16 + ln;

    const unsigned short* Ab = nullptr;
    const float*          Af = nullptr;
    if (GATHER) {
        int t = r >> 6, b = r & 63;
        size_t off = (size_t)xidx[b * TT + t] * K;
        if (mode) Af = (const float*)emb + off;
        else      Ab = (const unsigned short*)emb + off;
    } else {
        Ab = Abf + (size_t)r * K;
    }

    floatx4 acc = {0.f, 0.f, 0.f, 0.f};
    const int full = K >> 5, rem = K & 31;

    for (int kk = 0; kk < full; ++kk) {
        int k = kk * 32 + quad * 8;
        short8 a;
        if (GATHER && mode) {
            float4 f0 = *(const float4*)(Af + k);
            float4 f1 = *(const float4*)(Af + k + 4);
            a[0]=f2b(f0.x); a[1]=f2b(f0.y); a[2]=f2b(f0.z); a[3]=f2b(f0.w);
            a[4]=f2b(f1.x); a[5]=f2b(f1.y); a[6]=f2b(f1.z); a[7]=f2b(f1.w);
        } else if (GATHER) {
            const uint2* ap = (const uint2*)(Ab + k);
            ((uint2*)&a)[0] = ap[0];
            ((uint2*)&a)[1] = ap[1];
        } else {
            a = *(const short8*)(Ab + k);
        }
        short8 b = *(const short8*)&Wl[ln * KP2 + k];
        acc = __builtin_amdgcn_mfma_f32_16x16x32_bf16(a, b, acc, 0, 0, 0);
    }
    if (rem) {   // K=300 tail
        short8 a, b;
        for (int j = 0; j < 8; ++j) {
            int k = full * 32 + quad * 8 + j;
            bool in = (k < K);
            unsigned short raw = 0;
            if (in) raw = (GATHER && mode) ? f2b(Af[k]) : Ab[k];
            a[j] = (short)raw;
            b[j] = in ? (short)Wl[ln * KP2 + k] : (short)0;
        }
        acc = __builtin_amdgcn_mfma_f32_16x16x32_bf16(a, b, acc, 0, 0, 0);
    }

    const int col = n0 + ln;
    const float bvf = mode ? ((const float*)bias)[col]
                           : b2f(((const unsigned short*)bias)[col]);
    for (int rg = 0; rg < 4; ++rg) {
        int rr = mb * 64 + wave * 16 + quad * 4 + rg;
        C[(size_t)rr * HID + col] = f2b(acc[rg] + bvf);
    }
}

// ---------------------------------------------------------------------------
// scan: h[t] = tanh(pre[t] + h[t-1] @ Whh^T + bhh), t = 0..511
// 64 persistent WGs x 256 threads; WG owns 16 output cols (Whh slice 33 KB in
// LDS). h exchanged through the Infinity Cache with explicit agent-scope (sc1)
// loads/stores -- NO fences, so no buffer_wbl2/buffer_inv L2 nuking (round-3's
// 18 us/step killer). Ordering: sc1 h-stores -> s_waitcnt vmcnt(0) ->
// __syncthreads -> sc1 flag store; consumers poll flags with sc1 loads, then
// read h with sc1 loads (LLC is the coherence point; no stale L1/L2 involved).
// ---------------------------------------------------------------------------
__global__ __launch_bounds__(256)
void scan_kernel(const unsigned short* __restrict__ pre,  // [T][B][HID] bf16
                 unsigned short*       __restrict__ h,    // [T][B][HID] bf16
                 const void*           __restrict__ Whh,
                 const void*           __restrict__ bhh,
                 int* __restrict__ ctl, int flagOff)
{
    const int mode = ctl[0];
    int* flags = ctl + flagOff;                 // 64 flags, stride 4 ints
    __shared__ unsigned short Wl[16 * 1032];    // 33 KB
    const int tid = threadIdx.x;
    const int n0 = blockIdx.x * 16;

    if (mode) {
        const float* Wf = (const float*)Whh;
        for (int i = tid; i < 16 * 256; i += 256) {
            int nl = i >> 8, c = i & 255;
            float4 f = *(const float4*)(Wf + ((size_t)(n0 + nl) << 10) + c * 4);
            unsigned short* d = &Wl[nl * 1032 + c * 4];
            d[0] = f2b(f.x); d[1] = f2b(f.y); d[2] = f2b(f.z); d[3] = f2b(f.w);
        }
    } else {
        const unsigned short* Wb = (const unsigned short*)Whh;
        for (int i = tid; i < 16 * 128; i += 256) {
            int nl = i >> 7, c = i & 127;
            *(short8*)&Wl[nl * 1032 + c * 8] =
                *(const short8*)(Wb + ((size_t)(n0 + nl) << 10) + c * 8);
        }
    }
    __syncthreads();

    const int wave = tid >> 6, lane = tid & 63;
    const int quad = lane >> 4, ln = lane & 15;
    const int brow = wave * 16 + ln;      // A row (batch) for this lane
    const int ncol = n0 + ln;             // output col
    const float bvf = mode ? ((const float*)bhh)[ncol]
                           : b2f(((const unsigned short*)bhh)[ncol]);
    const int b0 = wave * 16 + quad * 4;
    const unsigned short* wl = &Wl[ln * 1032 + quad * 8];

    for (int t = 0; t < TT; ++t) {
        floatx4 acc = {0.f, 0.f, 0.f, 0.f};
        if (t > 0) {
            const unsigned short* hp = h + (size_t)(t - 1) * (BB * HID)
                                         + (size_t)brow * HID + quad * 8;
            short8 a[32];
            #pragma unroll
            for (int kk = 0; kk < 32; ++kk)
                asm volatile("global_load_dwordx4 %0, %1, off offset:%c2 sc1"
                             : "=v"(a[kk]) : "v"(hp), "i"(kk * 64) : "memory");
            WAIT_VM16(16, a);
            #pragma unroll
            for (int kk = 0; kk < 16; ++kk) {
                short8 b = *(const short8*)(wl + kk * 32);
                acc = __builtin_amdgcn_mfma_f32_16x16x32_bf16(a[kk], b, acc, 0, 0, 0);
            }
            WAIT_VM16(0, (a + 16));
            #pragma unroll
            for (int kk = 16; kk < 32; ++kk) {
                short8 b = *(const short8*)(wl + kk * 32);
                acc = __builtin_amdgcn_mfma_f32_16x16x32_bf16(a[kk], b, acc, 0, 0, 0);
            }
        }
        const unsigned short* pt = pre + (size_t)t * (BB * HID);
        unsigned short* ht = h + (size_t)t * (BB * HID);
        #pragma unroll
        for (int rg = 0; rg < 4; ++rg) {
            int bi = b0 + rg;
            float v = acc[rg] + b2f(pt[(size_t)bi * HID + ncol]) + bvf;
            unsigned int hv = f2b(tanhf(v));
            asm volatile("global_store_short %0, %1, off sc1"
                         :: "v"(ht + (size_t)bi * HID + ncol), "v"(hv) : "memory");
        }
        if (t < TT - 1) {
            asm volatile("s_waitcnt vmcnt(0)" ::: "memory");  // h[t] at LLC
            __syncthreads();                                   // whole WG done
            if (tid == 0) {
                int tv = t + 1;
                asm volatile("global_store_dword %0, %1, off sc1"
                             :: "v"(&flags[blockIdx.x * 4]), "v"(tv) : "memory");
            }
            if (tid < 64) {
                const int* fp = &flags[tid * 4];
                int v;
                do {
                    asm volatile("global_load_dword %0, %1, off sc1\n\t"
                                 "s_waitcnt vmcnt(0)"
                                 : "=v"(v) : "v"(fp) : "memory");
                } while (__any(v < t + 1));
            }
            __syncthreads();
        }
    }
}

// ---------------------------------------------------------------------------
// fc: out[b] = sigmoid(dot(h2[T-1][b], Wfc) + bfc)  -- fp32 out
// ---------------------------------------------------------------------------
__global__ __launch_bounds__(1024)
void fc_kernel(const unsigned short* __restrict__ h,
               const void* __restrict__ Wfc,
               const void* __restrict__ bfc,
               float* __restrict__ out,
               const int* __restrict__ ctl)
{
    const int mode = ctl[0];
    const int tid = threadIdx.x;
    const int b = tid >> 4, sub = tid & 15;
    const unsigned short* hr = h + (size_t)(TT - 1) * (BB * HID) + (size_t)b * HID;
    float s = 0.f;
    for (int k = sub; k < HID; k += 16) {
        float w = mode ? ((const float*)Wfc)[k]
                       : b2f(((const unsigned short*)Wfc)[k]);
        s += b2f(hr[k]) * w;
    }
    for (int off = 8; off; off >>= 1)
        s += __shfl_down(s, off, 16);
    if (sub == 0) {
        float bv = mode ? ((const float*)bfc)[0]
                        : b2f(((const unsigned short*)bfc)[0]);
        float z = s + bv;
        out[b] = 1.f / (1.f + expf(-z));
    }
}

// ---------------------------------------------------------------------------
extern "C" void kernel_launch(void* const* d_in, const int* in_sizes, int n_in,
                              void* d_out, int out_size, void* d_ws, size_t ws_size,
                              hipStream_t stream)
{
    const int*  x    = (const int*)d_in[0];
    const void* emb  = d_in[1];
    const void* Wih0 = d_in[2];
    const void* Whh0 = d_in[3];
    const void* bih0 = d_in[4];
    const void* bhh0 = d_in[5];
    const void* Wih1 = d_in[6];
    const void* Whh1 = d_in[7];
    const void* bih1 = d_in[8];
    const void* bhh1 = d_in[9];
    const void* Wfc  = d_in[10];
    const void* bfc  = d_in[11];
    float* out = (float*)d_out;

    char* ws = (char*)d_ws;
    int*            ctl  = (int*)ws;                          // 4 KiB region
    unsigned short* pre  = (unsigned short*)(ws + 4096);      // 64 MiB bf16
    unsigned short* hbuf = (unsigned short*)(ws + 4096 + (size_t)67108864);

    dim3 pgrid(HID / 16, M_ROWS / 64);

    // dtype detect + flag zeroing
    detect_kernel<<<dim3(1), dim3(64), 0, stream>>>(Whh0, ctl);
    // layer 0 input projection (embedding gather)
    proj_kernel<1><<<pgrid, dim3(256), 0, stream>>>(
        nullptr, x, emb, Wih0, bih0, pre, EMB, ctl);
    // layer 0 recurrence
    scan_kernel<<<dim3(64), dim3(256), 0, stream>>>(pre, hbuf, Whh0, bhh0, ctl, 64);
    // layer 1 input projection (reads h1, overwrites pre)
    proj_kernel<0><<<pgrid, dim3(256), 0, stream>>>(
        hbuf, nullptr, nullptr, Wih1, bih1, pre, HID, ctl);
    // layer 1 recurrence (in place over hbuf)
    scan_kernel<<<dim3(64), dim3(256), 0, stream>>>(pre, hbuf, Whh1, bhh1, ctl, 320);
    // final FC + sigmoid
    fc_kernel<<<dim3(1), dim3(1024), 0, stream>>>(hbuf, Wfc, bfc, out, ctl);
}

// Round 5
// 4810.472 us; speedup vs baseline: 4.0731x; 1.7832x over previous
//
#include <hip/hip_runtime.h>
#include <hip/hip_bf16.h>

#define VOCAB 50000
#define EMB   300
#define HID   1024
#define TT    512
#define BB    64
#define M_ROWS (BB * TT)   // 32768 rows, r = t*64 + b

// Block layout for h and pre: [t][kb=64][row=64][c=16] bf16
//   idx = ((t*64 + kb)*64 + row)*16 + c ; per-t slab = 65536 shorts = 128 KB
//   WG bx owns block kb=bx: a contiguous, line-aligned 2 KB tile per step.

typedef __attribute__((ext_vector_type(8))) short short8;
typedef __attribute__((ext_vector_type(4))) float floatx4;

__device__ inline float b2f(unsigned short u) {
    union { unsigned int i; float f; } v; v.i = ((unsigned int)u) << 16; return v.f;
}
__device__ inline unsigned short f2b(float f) {
    __hip_bfloat16 h = __float2bfloat16(f);
    return *reinterpret_cast<unsigned short*>(&h);
}

// Wait until only N of the outstanding vector loads remain, binding the first
// 16 fragments "+v" so the compiler cannot consume them earlier.
#define WAIT_VM16(N, A) asm volatile("s_waitcnt vmcnt(" #N ")"              \
    : "+v"((A)[0]), "+v"((A)[1]), "+v"((A)[2]), "+v"((A)[3]),               \
      "+v"((A)[4]), "+v"((A)[5]), "+v"((A)[6]), "+v"((A)[7]),               \
      "+v"((A)[8]), "+v"((A)[9]), "+v"((A)[10]), "+v"((A)[11]),             \
      "+v"((A)[12]), "+v"((A)[13]), "+v"((A)[14]), "+v"((A)[15])            \
    :: "memory")

// ---------------------------------------------------------------------------
// detect: bf16 (mode=0) vs fp32 (mode=1) input buffers (evidence: fp32).
// Also zeroes both scan-barrier flag regions.
// ctl ints: [0]=mode, flagsA=ctl+64 (64 flags stride 4), flagsB=ctl+320.
// ---------------------------------------------------------------------------
__global__ __launch_bounds__(64)
void detect_kernel(const void* __restrict__ W, int* __restrict__ ctl)
{
    const int tid = threadIdx.x;
    const unsigned short* p = (const unsigned short*)W;
    int bad = 0;
    for (int i = tid; i < 1024; i += 64) {
        float v = b2f(p[2 * i]);
        if (!(v > -0.5f && v < 0.5f)) bad++;
    }
    for (int off = 32; off; off >>= 1) bad += __shfl_down(bad, off);
    if (tid == 0) ctl[0] = (bad > 16) ? 1 : 0;
    for (int i = 64 + tid; i < 576; i += 64) ctl[i] = 0;
}

// ---------------------------------------------------------------------------
// proj (embedding gather): pre0[r][n] = bf16( emb[x]·W_ih0^T + b_ih0 ),
// written in BLOCK layout. 64 rows x 16 cols per WG.
// ---------------------------------------------------------------------------
__global__ __launch_bounds__(256)
void proj_kernel(const int*  __restrict__ xidx,
                 const void* __restrict__ emb,
                 const void* __restrict__ W,
                 const void* __restrict__ bias,
                 unsigned short* __restrict__ C,    // block layout bf16
                 const int* __restrict__ ctl)
{
    const int mode = ctl[0];
    const int K = EMB;
    __shared__ unsigned short Wl[16 * 312];          // KP2 = 312 >= 300, 16B rows
    const int tid = threadIdx.x;
    const int nb = blockIdx.x, mb = blockIdx.y;
    const int n0 = nb * 16;
    const int KP2 = 312;

    if (mode) {
        const float* Wf = (const float*)W;
        const int e4 = K >> 2, tot = 16 * e4;        // 300/4 = 75
        for (int i = tid; i < tot; i += 256) {
            int nl = i / e4, c = i - nl * e4;
            float4 f = *(const float4*)(Wf + (size_t)(n0 + nl) * K + c * 4);
            unsigned short* d = &Wl[nl * KP2 + c * 4];
            d[0] = f2b(f.x); d[1] = f2b(f.y); d[2] = f2b(f.z); d[3] = f2b(f.w);
        }
    } else {
        const unsigned short* Wb = (const unsigned short*)W;
        const int tot = 16 * K;
        for (int i = tid; i < tot; i += 256) {
            int nl = i / K, c = i - nl * K;
            Wl[nl * KP2 + c] = Wb[(size_t)(n0 + nl) * K + c];
        }
    }
    __syncthreads();

    const int wave = tid >> 6, lane = tid & 63;
    const int quad = lane >> 4, ln = lane & 15;
    const int r = mb * 64 + wave * 16 + ln;          // t = r>>6, b = r&63

    const unsigned short* Ab = nullptr;
    const float*          Af = nullptr;
    {
        int t = r >> 6, b = r & 63;
        size_t off = (size_t)xidx[b * TT + t] * K;
        if (mode) Af = (const float*)emb + off;
        else      Ab = (const unsigned short*)emb + off;
    }

    floatx4 acc = {0.f, 0.f, 0.f, 0.f};
    const int full = K >> 5;                         // 9
    for (int kk = 0; kk < full; ++kk) {
        int k = kk * 32 + quad * 8;
        short8 a;
        if (mode) {
            float4 f0 = *(const float4*)(Af + k);
            float4 f1 = *(const float4*)(Af + k + 4);
            a[0]=f2b(f0.x); a[1]=f2b(f0.y); a[2]=f2b(f0.z); a[3]=f2b(f0.w);
            a[4]=f2b(f1.x); a[5]=f2b(f1.y); a[6]=f2b(f1.z); a[7]=f2b(f1.w);
        } else {
            const uint2* ap = (const uint2*)(Ab + k);
            ((uint2*)&a)[0] = ap[0];
            ((uint2*)&a)[1] = ap[1];
        }
        short8 b = *(const short8*)&Wl[ln * KP2 + k];
        acc = __builtin_amdgcn_mfma_f32_16x16x32_bf16(a, b, acc, 0, 0, 0);
    }
    {   // K tail 288..299
        short8 a, b;
        for (int j = 0; j < 8; ++j) {
            int k = full * 32 + quad * 8 + j;
            bool in = (k < K);
            unsigned short raw = 0;
            if (in) raw = mode ? f2b(Af[k]) : Ab[k];
            a[j] = (short)raw;
            b[j] = in ? (short)Wl[ln * KP2 + k] : (short)0;
        }
        acc = __builtin_amdgcn_mfma_f32_16x16x32_bf16(a, b, acc, 0, 0, 0);
    }

    const int col = n0 + ln;
    const float bvf = mode ? ((const float*)bias)[col]
                           : b2f(((const unsigned short*)bias)[col]);
    // block layout: t = mb, kb = nb, row = wave*16+quad*4+rg, c = ln
    for (int rg = 0; rg < 4; ++rg) {
        size_t addr = ((size_t)mb * 64 + nb) * 1024
                    + (size_t)(wave * 16 + quad * 4 + rg) * 16 + ln;
        C[addr] = f2b(acc[rg] + bvf);
    }
}

// ---------------------------------------------------------------------------
// scan: h[t] = tanh(pre[t] + h[t-1]·Whh^T + bhh), t = 0..511.
// 64 persistent WGs x 256 thr; WG owns 16 cols (Whh slice 33 KB LDS).
// h in block layout via LLC (sc1, no fences): loads = 16B/lane from 512B-
// contiguous runs; stores = LDS-assembled 2 KB tile -> 128 x 16B sc1 stores
// (full 64B lines -> no LLC write-allocate RMW, round-4's FETCH bloat).
// FUSE=1 (layer 0): second MFMA chain vs W_ih1 slice computes
// pre1[t-1] = h1[t-1]·W_ih1^T + b_ih1 from the already-loaded fragments,
// overwriting the consumed pre0[t-1] block in place (WG-private) -> the
// separate proj1 kernel (h1 re-read + pre round trip) disappears.
// ---------------------------------------------------------------------------
template<int FUSE>
__global__ __launch_bounds__(256)
void scan_kernel(unsigned short* __restrict__ preB,   // block layout bf16
                 unsigned short* __restrict__ hB,     // block layout bf16
                 const void* __restrict__ Whh,
                 const void* __restrict__ bhh,
                 const void* __restrict__ Wnx,        // FUSE: W_ih1
                 const void* __restrict__ bnx,        // FUSE: b_ih1
                 int* __restrict__ ctl, int flagOff)
{
    const int mode = ctl[0];
    int* flags = ctl + flagOff;
    __shared__ unsigned short Wl[16 * 1032];
    __shared__ unsigned short Wn[FUSE ? 16 * 1032 : 16];
    __shared__ __align__(16) unsigned short hTile[1024];
    const int tid = threadIdx.x;
    const int bx  = blockIdx.x;
    const int n0  = bx * 16;

    if (mode) {
        const float* Wf = (const float*)Whh;
        for (int i = tid; i < 16 * 256; i += 256) {
            int nl = i >> 8, c = i & 255;
            float4 f = *(const float4*)(Wf + ((size_t)(n0 + nl) << 10) + c * 4);
            unsigned short* d = &Wl[nl * 1032 + c * 4];
            d[0] = f2b(f.x); d[1] = f2b(f.y); d[2] = f2b(f.z); d[3] = f2b(f.w);
        }
        if (FUSE) {
            const float* Wg = (const float*)Wnx;
            for (int i = tid; i < 16 * 256; i += 256) {
                int nl = i >> 8, c = i & 255;
                float4 f = *(const float4*)(Wg + ((size_t)(n0 + nl) << 10) + c * 4);
                unsigned short* d = &Wn[nl * 1032 + c * 4];
                d[0] = f2b(f.x); d[1] = f2b(f.y); d[2] = f2b(f.z); d[3] = f2b(f.w);
            }
        }
    } else {
        const unsigned short* Wb = (const unsigned short*)Whh;
        for (int i = tid; i < 16 * 128; i += 256) {
            int nl = i >> 7, c = i & 127;
            *(short8*)&Wl[nl * 1032 + c * 8] =
                *(const short8*)(Wb + ((size_t)(n0 + nl) << 10) + c * 8);
        }
        if (FUSE) {
            const unsigned short* Wg = (const unsigned short*)Wnx;
            for (int i = tid; i < 16 * 128; i += 256) {
                int nl = i >> 7, c = i & 127;
                *(short8*)&Wn[nl * 1032 + c * 8] =
                    *(const short8*)(Wg + ((size_t)(n0 + nl) << 10) + c * 8);
            }
        }
    }
    __syncthreads();

    const int wave = tid >> 6, lane = tid & 63;
    const int quad = lane >> 4, ln = lane & 15;
    const int brow = wave * 16 + ln;
    const int ncol = n0 + ln;
    const float bvf = mode ? ((const float*)bhh)[ncol]
                           : b2f(((const unsigned short*)bhh)[ncol]);
    const float bnf = FUSE ? (mode ? ((const float*)bnx)[ncol]
                                   : b2f(((const unsigned short*)bnx)[ncol]))
                           : 0.f;
    const int b0 = wave * 16 + quad * 4;
    const unsigned short* wl = &Wl[ln * 1032 + quad * 8];
    const unsigned short* wn = &Wn[ln * 1032 + quad * 8];
    // per-lane base offset within a t-slab for h loads:
    // k = kk*32 + quad*8 -> kb = 2kk + (quad>>1), c = (quad&1)*8, row = brow
    const int hoff = (quad >> 1) * 1024 + brow * 16 + (quad & 1) * 8;

    for (int t = 0; t < TT; ++t) {
        // prefetch pre[t] fragment early (plain loads, drain with h loads)
        const unsigned short* pp = preB + (size_t)t * 65536 + (size_t)bx * 1024
                                        + (size_t)b0 * 16 + ln;
        unsigned short pr0 = pp[0], pr1 = pp[16], pr2 = pp[32], pr3 = pp[48];

        floatx4 acc  = {0.f, 0.f, 0.f, 0.f};
        floatx4 acc2 = {0.f, 0.f, 0.f, 0.f};
        if (t > 0) {
            const unsigned short* hp = hB + (size_t)(t - 1) * 65536 + hoff;
            short8 a[32];
            #pragma unroll
            for (int kk = 0; kk < 32; ++kk)
                asm volatile("global_load_dwordx4 %0, %1, off sc1"
                             : "=v"(a[kk])
                             : "v"(hp + (size_t)kk * 2048) : "memory");
            WAIT_VM16(16, a);
            #pragma unroll
            for (int kk = 0; kk < 16; ++kk) {
                short8 b = *(const short8*)(wl + kk * 32);
                acc = __builtin_amdgcn_mfma_f32_16x16x32_bf16(a[kk], b, acc, 0, 0, 0);
                if (FUSE) {
                    short8 bn = *(const short8*)(wn + kk * 32);
                    acc2 = __builtin_amdgcn_mfma_f32_16x16x32_bf16(a[kk], bn, acc2, 0, 0, 0);
                }
            }
            WAIT_VM16(0, (a + 16));
            #pragma unroll
            for (int kk = 16; kk < 32; ++kk) {
                short8 b = *(const short8*)(wl + kk * 32);
                acc = __builtin_amdgcn_mfma_f32_16x16x32_bf16(a[kk], b, acc, 0, 0, 0);
                if (FUSE) {
                    short8 bn = *(const short8*)(wn + kk * 32);
                    acc2 = __builtin_amdgcn_mfma_f32_16x16x32_bf16(a[kk], bn, acc2, 0, 0, 0);
                }
            }
            if (FUSE) {   // pre1[t-1] for rows b0..b0+3, col ncol (WG-private block)
                unsigned short* q = preB + (size_t)(t - 1) * 65536
                                  + (size_t)bx * 1024 + (size_t)b0 * 16 + ln;
                q[0]  = f2b(acc2[0] + bnf);
                q[16] = f2b(acc2[1] + bnf);
                q[32] = f2b(acc2[2] + bnf);
                q[48] = f2b(acc2[3] + bnf);
            }
        }
        // h[t] into LDS tile (row-major 64x16)
        hTile[(b0 + 0) * 16 + ln] = f2b(tanhf(acc[0] + b2f(pr0) + bvf));
        hTile[(b0 + 1) * 16 + ln] = f2b(tanhf(acc[1] + b2f(pr1) + bvf));
        hTile[(b0 + 2) * 16 + ln] = f2b(tanhf(acc[2] + b2f(pr2) + bvf));
        hTile[(b0 + 3) * 16 + ln] = f2b(tanhf(acc[3] + b2f(pr3) + bvf));
        __syncthreads();
        if (tid < 128) {   // 2 KB contiguous -> 32 full 64B lines
            short8 hv = *(const short8*)&hTile[tid * 8];
            asm volatile("global_store_dwordx4 %0, %1, off sc1"
                         :: "v"(hB + (size_t)t * 65536 + (size_t)bx * 1024 + tid * 8),
                            "v"(hv) : "memory");
        }
        if (t < TT - 1) {
            asm volatile("s_waitcnt vmcnt(0)" ::: "memory");
            __syncthreads();
            if (tid == 0) {
                int tv = t + 1;
                asm volatile("global_store_dword %0, %1, off sc1"
                             :: "v"(&flags[bx * 4]), "v"(tv) : "memory");
            }
            if (tid < 64) {
                const int* fp = &flags[tid * 4];
                int v;
                do {
                    asm volatile("global_load_dword %0, %1, off sc1\n\t"
                                 "s_waitcnt vmcnt(0)"
                                 : "=v"(v) : "v"(fp) : "memory");
                } while (__any(v < t + 1));
            }
            __syncthreads();
        }
    }

    if (FUSE) {   // tail: pre1[511] needs full h[511] -> one more barrier round
        asm volatile("s_waitcnt vmcnt(0)" ::: "memory");
        __syncthreads();
        if (tid == 0) {
            int tv = TT;
            asm volatile("global_store_dword %0, %1, off sc1"
                         :: "v"(&flags[bx * 4]), "v"(tv) : "memory");
        }
        if (tid < 64) {
            const int* fp = &flags[tid * 4];
            int v;
            do {
                asm volatile("global_load_dword %0, %1, off sc1\n\t"
                             "s_waitcnt vmcnt(0)"
                             : "=v"(v) : "v"(fp) : "memory");
            } while (__any(v < TT));
        }
        __syncthreads();

        const unsigned short* hp = hB + (size_t)(TT - 1) * 65536 + hoff;
        short8 a[32];
        floatx4 acc2 = {0.f, 0.f, 0.f, 0.f};
        #pragma unroll
        for (int kk = 0; kk < 32; ++kk)
            asm volatile("global_load_dwordx4 %0, %1, off sc1"
                         : "=v"(a[kk])
                         : "v"(hp + (size_t)kk * 2048) : "memory");
        WAIT_VM16(16, a);
        #pragma unroll
        for (int kk = 0; kk < 16; ++kk) {
            short8 bn = *(const short8*)(wn + kk * 32);
            acc2 = __builtin_amdgcn_mfma_f32_16x16x32_bf16(a[kk], bn, acc2, 0, 0, 0);
        }
        WAIT_VM16(0, (a + 16));
        #pragma unroll
        for (int kk = 16; kk < 32; ++kk) {
            short8 bn = *(const short8*)(wn + kk * 32);
            acc2 = __builtin_amdgcn_mfma_f32_16x16x32_bf16(a[kk], bn, acc2, 0, 0, 0);
        }
        unsigned short* q = preB + (size_t)(TT - 1) * 65536
                          + (size_t)bx * 1024 + (size_t)b0 * 16 + ln;
        q[0]  = f2b(acc2[0] + bnf);
        q[16] = f2b(acc2[1] + bnf);
        q[32] = f2b(acc2[2] + bnf);
        q[48] = f2b(acc2[3] + bnf);
    }
}

// ---------------------------------------------------------------------------
// fc: out[b] = sigmoid(dot(h2[T-1][b], Wfc) + bfc)  -- fp32 out, block-layout h
// ---------------------------------------------------------------------------
__global__ __launch_bounds__(1024)
void fc_kernel(const unsigned short* __restrict__ h,
               const void* __restrict__ Wfc,
               const void* __restrict__ bfc,
               float* __restrict__ out,
               const int* __restrict__ ctl)
{
    const int mode = ctl[0];
    const int tid = threadIdx.x;
    const int b = tid >> 4, sub = tid & 15;
    const unsigned short* hr = h + (size_t)(TT - 1) * 65536 + b * 16 + sub;
    float s = 0.f;
    for (int j = 0; j < 64; ++j) {          // k = j*16 + sub
        float w = mode ? ((const float*)Wfc)[j * 16 + sub]
                       : b2f(((const unsigned short*)Wfc)[j * 16 + sub]);
        s += b2f(hr[(size_t)j * 1024]) * w;
    }
    for (int off = 8; off; off >>= 1)
        s += __shfl_down(s, off, 16);
    if (sub == 0) {
        float bv = mode ? ((const float*)bfc)[0]
                        : b2f(((const unsigned short*)bfc)[0]);
        out[b] = 1.f / (1.f + expf(-(s + bv)));
    }
}

// ---------------------------------------------------------------------------
extern "C" void kernel_launch(void* const* d_in, const int* in_sizes, int n_in,
                              void* d_out, int out_size, void* d_ws, size_t ws_size,
                              hipStream_t stream)
{
    const int*  x    = (const int*)d_in[0];
    const void* emb  = d_in[1];
    const void* Wih0 = d_in[2];
    const void* Whh0 = d_in[3];
    const void* bih0 = d_in[4];
    const void* bhh0 = d_in[5];
    const void* Wih1 = d_in[6];
    const void* Whh1 = d_in[7];
    const void* bih1 = d_in[8];
    const void* bhh1 = d_in[9];
    const void* Wfc  = d_in[10];
    const void* bfc  = d_in[11];
    float* out = (float*)d_out;

    char* ws = (char*)d_ws;
    int*            ctl  = (int*)ws;                          // 4 KiB
    unsigned short* pre  = (unsigned short*)(ws + 4096);      // 64 MiB (block)
    unsigned short* hbuf = (unsigned short*)(ws + 4096 + (size_t)67108864);

    // dtype detect + flag zeroing
    detect_kernel<<<dim3(1), dim3(64), 0, stream>>>(Whh0, ctl);
    // layer 0 input projection (embedding gather) -> pre (block layout)
    proj_kernel<<<dim3(64, 512), dim3(256), 0, stream>>>(
        x, emb, Wih0, bih0, pre, ctl);
    // layer 0 recurrence, fused with layer-1 input projection (pre1 in place)
    scan_kernel<1><<<dim3(64), dim3(256), 0, stream>>>(
        pre, hbuf, Whh0, bhh0, Wih1, bih1, ctl, 64);
    // layer 1 recurrence (h2 overwrites h1 slab-by-slab)
    scan_kernel<0><<<dim3(64), dim3(256), 0, stream>>>(
        pre, hbuf, Whh1, bhh1, nullptr, nullptr, ctl, 320);
    // final FC + sigmoid
    fc_kernel<<<dim3(1), dim3(1024), 0, stream>>>(hbuf, Wfc, bfc, out, ctl);
}